// Round 1
// baseline (258.257 us; speedup 1.0000x reference)
//
#include <hip/hip_runtime.h>
#include <hip/hip_bf16.h>
#include <math.h>

// ---- problem constants ----
#define B_ROWS 512
#define D_K    512
#define C_CLS  100000

#define S_SCALE 64.0f
// m = 0.5
#define COS_M 0.8775825618903728f
#define SIN_M 0.479425538604203f
#define TH_C  (-0.8775825618903728f)   // cos(pi - m)
#define MM_C  0.2397127693021015f      // sin(pi - m) * m

// ---- GEMM tile config ----
#define BM 256
#define BN 64
#define BK 64
#define LDP (BK + 8)                   // padded LDS row: 72 bf16 = 144 B (2-way bank alias only)
#define NCHUNK ((C_CLS + BN - 1) / BN) // 1563

typedef __attribute__((ext_vector_type(8))) short short8;
typedef __attribute__((ext_vector_type(4))) short short4v;
typedef __attribute__((ext_vector_type(4))) float f32x4;

__device__ inline unsigned short f2bf(float f) {
    unsigned int u = __float_as_uint(f);
    u += 0x7fffu + ((u >> 16) & 1u);
    return (unsigned short)(u >> 16);
}

// ---------------- kernel 0a: normalize x rows -> bf16 ----------------
__global__ __launch_bounds__(256) void xnorm_kernel(const float* __restrict__ x,
                                                    unsigned short* __restrict__ xnb) {
    const int row = blockIdx.x;
    const int t = threadIdx.x;
    float a = x[row * D_K + t];
    float b = x[row * D_K + t + 256];
    float s = a * a + b * b;
    s += __shfl_xor(s, 1);  s += __shfl_xor(s, 2);  s += __shfl_xor(s, 4);
    s += __shfl_xor(s, 8);  s += __shfl_xor(s, 16); s += __shfl_xor(s, 32);
    __shared__ float sS[4];
    __shared__ float rn_sh;
    if ((t & 63) == 0) sS[t >> 6] = s;
    __syncthreads();
    if (t == 0) rn_sh = 1.0f / sqrtf(sS[0] + sS[1] + sS[2] + sS[3]);
    __syncthreads();
    const float rn = rn_sh;
    xnb[row * D_K + t]       = f2bf(a * rn);
    xnb[row * D_K + t + 256] = f2bf(b * rn);
}

// ---------------- kernel 0b: weight row rnorm ----------------
__global__ __launch_bounds__(256) void wnorm_kernel(const float* __restrict__ w,
                                                    float* __restrict__ rnorm) {
    const int wv = threadIdx.x >> 6;
    const int lane = threadIdx.x & 63;
    const int c = blockIdx.x * 4 + wv;
    const float* row = w + (size_t)c * D_K;
    float4 v1 = *(const float4*)&row[lane * 8];
    float4 v2 = *(const float4*)&row[lane * 8 + 4];
    float s = v1.x * v1.x + v1.y * v1.y + v1.z * v1.z + v1.w * v1.w
            + v2.x * v2.x + v2.y * v2.y + v2.z * v2.z + v2.w * v2.w;
    s += __shfl_xor(s, 1);  s += __shfl_xor(s, 2);  s += __shfl_xor(s, 4);
    s += __shfl_xor(s, 8);  s += __shfl_xor(s, 16); s += __shfl_xor(s, 32);
    if (lane == 0) rnorm[c] = 1.0f / sqrtf(s);
}

// ---------------- kernel 1: fused GEMM + margin + chunk lse partials ----------------
__global__ __launch_bounds__(256) void gemm_fused_kernel(
        const unsigned short* __restrict__ xnb,   // [512][512] bf16, normalized
        const float* __restrict__ w,              // [100000][512] fp32 raw
        const float* __restrict__ rnorm,          // [100000]
        const int* __restrict__ tgt,              // [512]
        float2* __restrict__ partials,            // [512][NCHUNK] (max, sumexp)
        float* __restrict__ tlogit) {             // [512]
    const int t    = threadIdx.x;
    const int lane = t & 63;
    const int wid  = t >> 6;
    const int C0   = blockIdx.x * BN;   // class chunk base
    const int R0   = blockIdx.y * BM;   // row block base

    __shared__ short la[BM][LDP];
    __shared__ short lb[BN][LDP];
    __shared__ int   ltgt[BM];
    __shared__ float lrn[BN];

    ltgt[t] = tgt[R0 + t];
    if (t < BN) {
        int c = C0 + t;
        lrn[t] = (c < C_CLS) ? rnorm[c] : 0.0f;
    }

    f32x4 acc[4][4];
#pragma unroll
    for (int m = 0; m < 4; ++m)
#pragma unroll
        for (int n = 0; n < 4; ++n) acc[m][n] = (f32x4){0.f, 0.f, 0.f, 0.f};

    const int apiece = t & 7;          // 8 x 16B per A row
    const int arbase = t >> 3;         // 32 rows / pass
    const int wpiece = t & 15;         // 16 x float4 per W row
    const int wrbase = t >> 4;         // 16 rows / pass

    for (int k0 = 0; k0 < D_K; k0 += BK) {
        __syncthreads();
        // stage A (bf16 256x64)
#pragma unroll
        for (int p = 0; p < 8; ++p) {
            int r = arbase + p * 32;
            int4 v = *(const int4*)&xnb[(size_t)(R0 + r) * D_K + k0 + apiece * 8];
            *(int4*)&la[r][apiece * 8] = v;
        }
        // stage W (fp32 64x64 -> normalized bf16)
#pragma unroll
        for (int p = 0; p < 4; ++p) {
            int r = wrbase + p * 16;
            int c = C0 + r;
            float4 v = {0.f, 0.f, 0.f, 0.f};
            if (c < C_CLS) v = *(const float4*)&w[(size_t)c * D_K + k0 + wpiece * 4];
            float rn = lrn[r];
            short4v h;
            h.x = (short)f2bf(v.x * rn);
            h.y = (short)f2bf(v.y * rn);
            h.z = (short)f2bf(v.z * rn);
            h.w = (short)f2bf(v.w * rn);
            *(short4v*)&lb[r][wpiece * 4] = h;
        }
        __syncthreads();
        // compute: each wave does 64x64 tile (rows wid*64..+63)
#pragma unroll
        for (int kk = 0; kk < 2; ++kk) {
            const int klo = kk * 32 + (lane >> 4) * 8;
            short8 af[4], bfr[4];
#pragma unroll
            for (int m = 0; m < 4; ++m)
                af[m] = *(const short8*)&la[wid * 64 + m * 16 + (lane & 15)][klo];
#pragma unroll
            for (int n = 0; n < 4; ++n)
                bfr[n] = *(const short8*)&lb[n * 16 + (lane & 15)][klo];
#pragma unroll
            for (int m = 0; m < 4; ++m)
#pragma unroll
                for (int n = 0; n < 4; ++n)
                    acc[m][n] = __builtin_amdgcn_mfma_f32_16x16x32_bf16(
                        af[m], bfr[n], acc[m][n], 0, 0, 0);
        }
    }

    // ---- epilogue: margin + per-row (max, sumexp) over this 64-col chunk ----
    const int col0 = lane & 15;
#pragma unroll
    for (int m16 = 0; m16 < 4; ++m16) {
#pragma unroll
        for (int j = 0; j < 4; ++j) {
            const int rloc = wid * 64 + m16 * 16 + ((lane >> 4) << 2) + j;
            const int b = R0 + rloc;
            const int tg = ltgt[rloc];
            float v[4];
#pragma unroll
            for (int n16 = 0; n16 < 4; ++n16) {
                const int c = C0 + n16 * 16 + col0;
                const float cs = acc[m16][n16][j];
                float logit;
                if (c < C_CLS) {
                    logit = S_SCALE * cs;
                    if (c == tg) {
                        float c2 = 1.0f - cs * cs;
                        c2 = fminf(fmaxf(c2, 0.0f), 1.0f);
                        float sine = sqrtf(c2);
                        float phi = cs * COS_M - sine * SIN_M;
                        phi = (cs > TH_C) ? phi : (cs - MM_C);
                        logit = S_SCALE * phi;
                        tlogit[b] = logit;
                    }
                } else {
                    logit = -INFINITY;
                }
                v[n16] = logit;
            }
            float rm = fmaxf(fmaxf(v[0], v[1]), fmaxf(v[2], v[3]));
            rm = fmaxf(rm, __shfl_xor(rm, 1));
            rm = fmaxf(rm, __shfl_xor(rm, 2));
            rm = fmaxf(rm, __shfl_xor(rm, 4));
            rm = fmaxf(rm, __shfl_xor(rm, 8));
            float sm = expf(v[0] - rm) + expf(v[1] - rm) + expf(v[2] - rm) + expf(v[3] - rm);
            sm += __shfl_xor(sm, 1);
            sm += __shfl_xor(sm, 2);
            sm += __shfl_xor(sm, 4);
            sm += __shfl_xor(sm, 8);
            if (col0 == 0)
                partials[(size_t)b * NCHUNK + blockIdx.x] = make_float2(rm, sm);
        }
    }
}

// ---------------- kernel 2: per-row lse over chunks ----------------
__global__ __launch_bounds__(256) void row_lse_kernel(const float2* __restrict__ partials,
                                                      const float* __restrict__ tlogit,
                                                      float* __restrict__ rowloss) {
    const int b = blockIdx.x;
    const int t = threadIdx.x;
    float M = -INFINITY, Ssum = 0.0f;
    for (int ch = t; ch < NCHUNK; ch += 256) {
        float2 p = partials[(size_t)b * NCHUNK + ch];
        if (p.x > M) {
            Ssum = Ssum * expf(M - p.x) + p.y;
            M = p.x;
        } else {
            Ssum += p.y * expf(p.x - M);
        }
    }
#pragma unroll
    for (int mask = 1; mask < 64; mask <<= 1) {
        float Mo = __shfl_xor(M, mask);
        float So = __shfl_xor(Ssum, mask);
        float Mn = fmaxf(M, Mo);
        Ssum = Ssum * expf(M - Mn) + So * expf(Mo - Mn);
        M = Mn;
    }
    __shared__ float sM[4], sS[4];
    if ((t & 63) == 0) { sM[t >> 6] = M; sS[t >> 6] = Ssum; }
    __syncthreads();
    if (t == 0) {
        float Mf = sM[0], Sf = sS[0];
#pragma unroll
        for (int wv = 1; wv < 4; ++wv) {
            float Mn = fmaxf(Mf, sM[wv]);
            Sf = Sf * expf(Mf - Mn) + sS[wv] * expf(sM[wv] - Mn);
            Mf = Mn;
        }
        float lse = Mf + logf(Sf);
        rowloss[b] = lse - tlogit[b];
    }
}

// ---------------- kernel 3: mean ----------------
__global__ __launch_bounds__(256) void final_mean_kernel(const float* __restrict__ rowloss,
                                                         float* __restrict__ out) {
    const int t = threadIdx.x;
    float s = rowloss[t] + rowloss[t + 256];
    s += __shfl_xor(s, 1);  s += __shfl_xor(s, 2);  s += __shfl_xor(s, 4);
    s += __shfl_xor(s, 8);  s += __shfl_xor(s, 16); s += __shfl_xor(s, 32);
    __shared__ float sS[4];
    if ((t & 63) == 0) sS[t >> 6] = s;
    __syncthreads();
    if (t == 0) out[0] = (sS[0] + sS[1] + sS[2] + sS[3]) * (1.0f / (float)B_ROWS);
}

extern "C" void kernel_launch(void* const* d_in, const int* in_sizes, int n_in,
                              void* d_out, int out_size, void* d_ws, size_t ws_size,
                              hipStream_t stream) {
    const float* x = (const float*)d_in[0];
    const float* w = (const float*)d_in[1];
    const int* tgt = (const int*)d_in[2];
    float* out = (float*)d_out;

    char* ws = (char*)d_ws;
    size_t off = 0;
    unsigned short* xnb = (unsigned short*)(ws + off); off += (size_t)B_ROWS * D_K * 2;       // 512 KB
    off = (off + 255) & ~(size_t)255;
    float* rnorm = (float*)(ws + off); off += (size_t)C_CLS * 4;                              // 400 KB
    off = (off + 255) & ~(size_t)255;
    float2* partials = (float2*)(ws + off); off += (size_t)B_ROWS * NCHUNK * sizeof(float2);  // 6.4 MB
    off = (off + 255) & ~(size_t)255;
    float* tlogit = (float*)(ws + off); off += B_ROWS * 4;
    off = (off + 255) & ~(size_t)255;
    float* rowloss = (float*)(ws + off); off += B_ROWS * 4;

    xnorm_kernel<<<B_ROWS, 256, 0, stream>>>(x, xnb);
    wnorm_kernel<<<C_CLS / 4, 256, 0, stream>>>(w, rnorm);
    dim3 grid(NCHUNK, B_ROWS / BM);
    gemm_fused_kernel<<<grid, 256, 0, stream>>>(xnb, w, rnorm, tgt, partials, tlogit);
    row_lse_kernel<<<B_ROWS, 256, 0, stream>>>(partials, tlogit, rowloss);
    final_mean_kernel<<<1, 256, 0, stream>>>(rowloss, out);
}

// Round 2
// 200.289 us; speedup vs baseline: 1.2894x; 1.2894x over previous
//
#include <hip/hip_runtime.h>
#include <hip/hip_bf16.h>
#include <math.h>

// ---- problem constants ----
#define B_ROWS 512
#define D_K    512
#define C_CLS  100000

#define S_SCALE 64.0f
#define COS_M 0.8775825618903728f
#define SIN_M 0.479425538604203f
#define TH_C  (-0.8775825618903728f)   // cos(pi - m)
#define MM_C  0.2397127693021015f      // sin(pi - m) * m

// ---- GEMM tile config ----
#define BM 256
#define BN 64
#define BK 64
#define LDP (BK + 8)                   // old path padded LDS row
#define NCHUNK ((C_CLS + BN - 1) / BN) // 1563

typedef __attribute__((ext_vector_type(8))) short short8;
typedef __attribute__((ext_vector_type(4))) short short4v;
typedef __attribute__((ext_vector_type(4))) float f32x4;

__device__ inline unsigned short f2bf(float f) {
    unsigned int u = __float_as_uint(f);
    u += 0x7fffu + ((u >> 16) & 1u);
    return (unsigned short)(u >> 16);
}

__device__ inline void gload16(const void* g, void* lds) {
    __builtin_amdgcn_global_load_lds(
        (const __attribute__((address_space(1))) unsigned int*)g,
        (__attribute__((address_space(3))) unsigned int*)lds, 16, 0, 0);
}

// ---------------- kernel 0a: normalize x rows -> bf16 ----------------
__global__ __launch_bounds__(256) void xnorm_kernel(const float* __restrict__ x,
                                                    unsigned short* __restrict__ xnb) {
    const int row = blockIdx.x;
    const int t = threadIdx.x;
    float a = x[row * D_K + t];
    float b = x[row * D_K + t + 256];
    float s = a * a + b * b;
    s += __shfl_xor(s, 1);  s += __shfl_xor(s, 2);  s += __shfl_xor(s, 4);
    s += __shfl_xor(s, 8);  s += __shfl_xor(s, 16); s += __shfl_xor(s, 32);
    __shared__ float sS[4];
    __shared__ float rn_sh;
    if ((t & 63) == 0) sS[t >> 6] = s;
    __syncthreads();
    if (t == 0) rn_sh = 1.0f / sqrtf(sS[0] + sS[1] + sS[2] + sS[3]);
    __syncthreads();
    const float rn = rn_sh;
    xnb[row * D_K + t]       = f2bf(a * rn);
    xnb[row * D_K + t + 256] = f2bf(b * rn);
}

// ---------------- NEW kernel 0b: normalize W rows -> bf16 (single pass) ----------------
__global__ __launch_bounds__(256) void wnormconv_kernel(const float* __restrict__ w,
                                                        unsigned short* __restrict__ wn) {
    const int wid = threadIdx.x >> 6;
    const int lane = threadIdx.x & 63;
    const int c = blockIdx.x * 4 + wid;
    const float* row = w + (size_t)c * D_K;
    float4 v1 = *(const float4*)&row[lane * 8];
    float4 v2 = *(const float4*)&row[lane * 8 + 4];
    float s = v1.x * v1.x + v1.y * v1.y + v1.z * v1.z + v1.w * v1.w
            + v2.x * v2.x + v2.y * v2.y + v2.z * v2.z + v2.w * v2.w;
    s += __shfl_xor(s, 1);  s += __shfl_xor(s, 2);  s += __shfl_xor(s, 4);
    s += __shfl_xor(s, 8);  s += __shfl_xor(s, 16); s += __shfl_xor(s, 32);
    const float rn = 1.0f / sqrtf(s);
    short8 h;
    h[0] = (short)f2bf(v1.x * rn);
    h[1] = (short)f2bf(v1.y * rn);
    h[2] = (short)f2bf(v1.z * rn);
    h[3] = (short)f2bf(v1.w * rn);
    h[4] = (short)f2bf(v2.x * rn);
    h[5] = (short)f2bf(v2.y * rn);
    h[6] = (short)f2bf(v2.z * rn);
    h[7] = (short)f2bf(v2.w * rn);
    *(short8*)&wn[(size_t)c * D_K + lane * 8] = h;
}

// ---------------- NEW kernel 1: pure-bf16 GEMM (global_load_lds + XOR swizzle) ----------------
// LDS layout: linear la[256][128B], lb[64][128B]; physical byte of logical (row, c) is
// row*128 + (c ^ ((row&7)<<4)).  Stage writes linear LDS (wave base + lane*16); the
// inverse swizzle is applied to the per-lane GLOBAL source column (m173/m201 pattern).
__global__ __launch_bounds__(256) void gemm_bf16_kernel(
        const unsigned short* __restrict__ xnb,   // [512][512] bf16 normalized
        const unsigned short* __restrict__ wn,    // [100000][512] bf16 normalized
        const int* __restrict__ tgt,              // [512]
        float2* __restrict__ partials,            // [512][NCHUNK] (max, sumexp)
        float* __restrict__ tlogit) {             // [512]
    const int t    = threadIdx.x;
    const int lane = t & 63;
    const int wid  = t >> 6;
    const int C0   = blockIdx.x * BN;
    const int R0   = blockIdx.y * BM;

    __shared__ short la[BM * BK];   // 32 KB
    __shared__ short lb[BN * BK];   // 8 KB
    __shared__ int   ltgt[BM];

    ltgt[t] = tgt[R0 + t];

    f32x4 acc[4][4];
#pragma unroll
    for (int m = 0; m < 4; ++m)
#pragma unroll
        for (int n = 0; n < 4; ++n) acc[m][n] = (f32x4){0.f, 0.f, 0.f, 0.f};

    const int l8 = lane >> 3;                      // 0..7 : row within 8-row chunk
    const int cbs = ((lane & 7) ^ l8) << 4;        // swizzled source byte-col
    const char* gA = (const char*)xnb;
    const char* gB = (const char*)wn;
    char* sA = (char*)la;
    char* sB = (char*)lb;

    for (int k0 = 0; k0 < D_K; k0 += BK) {
        __syncthreads();
        // stage A: 256x64 bf16 = 32 KB, 8 insts x (256 lanes x 16B)
#pragma unroll
        for (int i = 0; i < 8; ++i) {
            const int row = i * 32 + wid * 8 + l8;
            gload16(gA + (size_t)(R0 + row) * 1024 + k0 * 2 + cbs,
                    sA + (i * 4 + wid) * 1024);
        }
        // stage B: 64x64 bf16 = 8 KB, 2 insts
#pragma unroll
        for (int j = 0; j < 2; ++j) {
            const int row = j * 32 + wid * 8 + l8;
            int c = C0 + row;
            if (c > C_CLS - 1) c = C_CLS - 1;      // clamp; masked in epilogue
            gload16(gB + (size_t)c * 1024 + k0 * 2 + cbs,
                    sB + (j * 4 + wid) * 1024);
        }
        asm volatile("s_waitcnt vmcnt(0)" ::: "memory");
        __syncthreads();

        const int xorv  = (lane & 7) << 4;
        const int cl    = lane & 15;
        const int khalf = (lane >> 4) << 4;        // byte offset of this lane-group's k-slot
#pragma unroll
        for (int kk = 0; kk < 2; ++kk) {
            const int coff = (kk * 64 + khalf) ^ xorv;
            short8 af[4], bfr[4];
#pragma unroll
            for (int m = 0; m < 4; ++m) {
                const int r = wid * 64 + m * 16 + cl;
                af[m] = *(const short8*)(sA + r * 128 + coff);
            }
#pragma unroll
            for (int n = 0; n < 4; ++n) {
                const int r = n * 16 + cl;
                bfr[n] = *(const short8*)(sB + r * 128 + coff);
            }
#pragma unroll
            for (int m = 0; m < 4; ++m)
#pragma unroll
                for (int n = 0; n < 4; ++n)
                    acc[m][n] = __builtin_amdgcn_mfma_f32_16x16x32_bf16(
                        af[m], bfr[n], acc[m][n], 0, 0, 0);
        }
    }

    // ---- epilogue: margin + per-row (max, sumexp) over this 64-col chunk ----
    const int col0 = lane & 15;
#pragma unroll
    for (int m16 = 0; m16 < 4; ++m16) {
#pragma unroll
        for (int j = 0; j < 4; ++j) {
            const int rloc = wid * 64 + m16 * 16 + ((lane >> 4) << 2) + j;
            const int b = R0 + rloc;
            const int tg = ltgt[rloc];
            float v[4];
#pragma unroll
            for (int n16 = 0; n16 < 4; ++n16) {
                const int c = C0 + n16 * 16 + col0;
                const float cs = acc[m16][n16][j];
                float logit;
                if (c < C_CLS) {
                    logit = S_SCALE * cs;
                    if (c == tg) {
                        float c2 = 1.0f - cs * cs;
                        c2 = fminf(fmaxf(c2, 0.0f), 1.0f);
                        float sine = sqrtf(c2);
                        float phi = cs * COS_M - sine * SIN_M;
                        phi = (cs > TH_C) ? phi : (cs - MM_C);
                        logit = S_SCALE * phi;
                        tlogit[b] = logit;
                    }
                } else {
                    logit = -INFINITY;
                }
                v[n16] = logit;
            }
            float rm = fmaxf(fmaxf(v[0], v[1]), fmaxf(v[2], v[3]));
            rm = fmaxf(rm, __shfl_xor(rm, 1));
            rm = fmaxf(rm, __shfl_xor(rm, 2));
            rm = fmaxf(rm, __shfl_xor(rm, 4));
            rm = fmaxf(rm, __shfl_xor(rm, 8));
            float sm = expf(v[0] - rm) + expf(v[1] - rm) + expf(v[2] - rm) + expf(v[3] - rm);
            sm += __shfl_xor(sm, 1);
            sm += __shfl_xor(sm, 2);
            sm += __shfl_xor(sm, 4);
            sm += __shfl_xor(sm, 8);
            if (col0 == 0)
                partials[(size_t)b * NCHUNK + blockIdx.x] = make_float2(rm, sm);
        }
    }
}

// ================= OLD PATH (fallback if ws too small) =================
__global__ __launch_bounds__(256) void wnorm_kernel(const float* __restrict__ w,
                                                    float* __restrict__ rnorm) {
    const int wv = threadIdx.x >> 6;
    const int lane = threadIdx.x & 63;
    const int c = blockIdx.x * 4 + wv;
    const float* row = w + (size_t)c * D_K;
    float4 v1 = *(const float4*)&row[lane * 8];
    float4 v2 = *(const float4*)&row[lane * 8 + 4];
    float s = v1.x * v1.x + v1.y * v1.y + v1.z * v1.z + v1.w * v1.w
            + v2.x * v2.x + v2.y * v2.y + v2.z * v2.z + v2.w * v2.w;
    s += __shfl_xor(s, 1);  s += __shfl_xor(s, 2);  s += __shfl_xor(s, 4);
    s += __shfl_xor(s, 8);  s += __shfl_xor(s, 16); s += __shfl_xor(s, 32);
    if (lane == 0) rnorm[c] = 1.0f / sqrtf(s);
}

__global__ __launch_bounds__(256) void gemm_fused_kernel(
        const unsigned short* __restrict__ xnb,
        const float* __restrict__ w,
        const float* __restrict__ rnorm,
        const int* __restrict__ tgt,
        float2* __restrict__ partials,
        float* __restrict__ tlogit) {
    const int t    = threadIdx.x;
    const int lane = t & 63;
    const int wid  = t >> 6;
    const int C0   = blockIdx.x * BN;
    const int R0   = blockIdx.y * BM;

    __shared__ short la[BM][LDP];
    __shared__ short lb[BN][LDP];
    __shared__ int   ltgt[BM];
    __shared__ float lrn[BN];

    ltgt[t] = tgt[R0 + t];
    if (t < BN) {
        int c = C0 + t;
        lrn[t] = (c < C_CLS) ? rnorm[c] : 0.0f;
    }

    f32x4 acc[4][4];
#pragma unroll
    for (int m = 0; m < 4; ++m)
#pragma unroll
        for (int n = 0; n < 4; ++n) acc[m][n] = (f32x4){0.f, 0.f, 0.f, 0.f};

    const int apiece = t & 7;
    const int arbase = t >> 3;
    const int wpiece = t & 15;
    const int wrbase = t >> 4;

    for (int k0 = 0; k0 < D_K; k0 += BK) {
        __syncthreads();
#pragma unroll
        for (int p = 0; p < 8; ++p) {
            int r = arbase + p * 32;
            int4 v = *(const int4*)&xnb[(size_t)(R0 + r) * D_K + k0 + apiece * 8];
            *(int4*)&la[r][apiece * 8] = v;
        }
#pragma unroll
        for (int p = 0; p < 4; ++p) {
            int r = wrbase + p * 16;
            int c = C0 + r;
            float4 v = {0.f, 0.f, 0.f, 0.f};
            if (c < C_CLS) v = *(const float4*)&w[(size_t)c * D_K + k0 + wpiece * 4];
            float rn = lrn[r];
            short4v h;
            h.x = (short)f2bf(v.x * rn);
            h.y = (short)f2bf(v.y * rn);
            h.z = (short)f2bf(v.z * rn);
            h.w = (short)f2bf(v.w * rn);
            *(short4v*)&lb[r][wpiece * 4] = h;
        }
        __syncthreads();
#pragma unroll
        for (int kk = 0; kk < 2; ++kk) {
            const int klo = kk * 32 + (lane >> 4) * 8;
            short8 af[4], bfr[4];
#pragma unroll
            for (int m = 0; m < 4; ++m)
                af[m] = *(const short8*)&la[wid * 64 + m * 16 + (lane & 15)][klo];
#pragma unroll
            for (int n = 0; n < 4; ++n)
                bfr[n] = *(const short8*)&lb[n * 16 + (lane & 15)][klo];
#pragma unroll
            for (int m = 0; m < 4; ++m)
#pragma unroll
                for (int n = 0; n < 4; ++n)
                    acc[m][n] = __builtin_amdgcn_mfma_f32_16x16x32_bf16(
                        af[m], bfr[n], acc[m][n], 0, 0, 0);
        }
    }

    const int col0 = lane & 15;
#pragma unroll
    for (int m16 = 0; m16 < 4; ++m16) {
#pragma unroll
        for (int j = 0; j < 4; ++j) {
            const int rloc = wid * 64 + m16 * 16 + ((lane >> 4) << 2) + j;
            const int b = R0 + rloc;
            const int tg = ltgt[rloc];
            float v[4];
#pragma unroll
            for (int n16 = 0; n16 < 4; ++n16) {
                const int c = C0 + n16 * 16 + col0;
                const float cs = acc[m16][n16][j];
                float logit;
                if (c < C_CLS) {
                    logit = S_SCALE * cs;
                    if (c == tg) {
                        float c2 = 1.0f - cs * cs;
                        c2 = fminf(fmaxf(c2, 0.0f), 1.0f);
                        float sine = sqrtf(c2);
                        float phi = cs * COS_M - sine * SIN_M;
                        phi = (cs > TH_C) ? phi : (cs - MM_C);
                        logit = S_SCALE * phi;
                        tlogit[b] = logit;
                    }
                } else {
                    logit = -INFINITY;
                }
                v[n16] = logit;
            }
            float rm = fmaxf(fmaxf(v[0], v[1]), fmaxf(v[2], v[3]));
            rm = fmaxf(rm, __shfl_xor(rm, 1));
            rm = fmaxf(rm, __shfl_xor(rm, 2));
            rm = fmaxf(rm, __shfl_xor(rm, 4));
            rm = fmaxf(rm, __shfl_xor(rm, 8));
            float sm = expf(v[0] - rm) + expf(v[1] - rm) + expf(v[2] - rm) + expf(v[3] - rm);
            sm += __shfl_xor(sm, 1);
            sm += __shfl_xor(sm, 2);
            sm += __shfl_xor(sm, 4);
            sm += __shfl_xor(sm, 8);
            if (col0 == 0)
                partials[(size_t)b * NCHUNK + blockIdx.x] = make_float2(rm, sm);
        }
    }
}

// ---------------- kernel 2: per-row lse over chunks ----------------
__global__ __launch_bounds__(256) void row_lse_kernel(const float2* __restrict__ partials,
                                                      const float* __restrict__ tlogit,
                                                      float* __restrict__ rowloss) {
    const int b = blockIdx.x;
    const int t = threadIdx.x;
    float M = -INFINITY, Ssum = 0.0f;
    for (int ch = t; ch < NCHUNK; ch += 256) {
        float2 p = partials[(size_t)b * NCHUNK + ch];
        if (p.x > M) {
            Ssum = Ssum * expf(M - p.x) + p.y;
            M = p.x;
        } else {
            Ssum += p.y * expf(p.x - M);
        }
    }
#pragma unroll
    for (int mask = 1; mask < 64; mask <<= 1) {
        float Mo = __shfl_xor(M, mask);
        float So = __shfl_xor(Ssum, mask);
        float Mn = fmaxf(M, Mo);
        Ssum = Ssum * expf(M - Mn) + So * expf(Mo - Mn);
        M = Mn;
    }
    __shared__ float sM[4], sS[4];
    if ((t & 63) == 0) { sM[t >> 6] = M; sS[t >> 6] = Ssum; }
    __syncthreads();
    if (t == 0) {
        float Mf = sM[0], Sf = sS[0];
#pragma unroll
        for (int wv = 1; wv < 4; ++wv) {
            float Mn = fmaxf(Mf, sM[wv]);
            Sf = Sf * expf(Mf - Mn) + sS[wv] * expf(sM[wv] - Mn);
            Mf = Mn;
        }
        float lse = Mf + logf(Sf);
        rowloss[b] = lse - tlogit[b];
    }
}

// ---------------- kernel 3: mean ----------------
__global__ __launch_bounds__(256) void final_mean_kernel(const float* __restrict__ rowloss,
                                                         float* __restrict__ out) {
    const int t = threadIdx.x;
    float s = rowloss[t] + rowloss[t + 256];
    s += __shfl_xor(s, 1);  s += __shfl_xor(s, 2);  s += __shfl_xor(s, 4);
    s += __shfl_xor(s, 8);  s += __shfl_xor(s, 16); s += __shfl_xor(s, 32);
    __shared__ float sS[4];
    if ((t & 63) == 0) sS[t >> 6] = s;
    __syncthreads();
    if (t == 0) out[0] = (sS[0] + sS[1] + sS[2] + sS[3]) * (1.0f / (float)B_ROWS);
}

extern "C" void kernel_launch(void* const* d_in, const int* in_sizes, int n_in,
                              void* d_out, int out_size, void* d_ws, size_t ws_size,
                              hipStream_t stream) {
    const float* x = (const float*)d_in[0];
    const float* w = (const float*)d_in[1];
    const int* tgt = (const int*)d_in[2];
    float* out = (float*)d_out;

    char* ws = (char*)d_ws;

    // new-path workspace: xnb + wn(bf16) + partials + tlogit + rowloss
    const size_t sz_xnb = (size_t)B_ROWS * D_K * 2;
    const size_t sz_wn  = (size_t)C_CLS * D_K * 2;
    const size_t sz_par = (size_t)B_ROWS * NCHUNK * sizeof(float2);
    const size_t need_new = sz_xnb + 256 + sz_wn + 256 + sz_par + 256 + 4096 + 4096 + 1024;

    if (ws_size >= need_new) {
        size_t off = 0;
        unsigned short* xnb = (unsigned short*)(ws + off); off += sz_xnb;
        off = (off + 255) & ~(size_t)255;
        unsigned short* wn = (unsigned short*)(ws + off); off += sz_wn;
        off = (off + 255) & ~(size_t)255;
        float2* partials = (float2*)(ws + off); off += sz_par;
        off = (off + 255) & ~(size_t)255;
        float* tlogit = (float*)(ws + off); off += 4096;
        float* rowloss = (float*)(ws + off); off += 4096;

        xnorm_kernel<<<B_ROWS, 256, 0, stream>>>(x, xnb);
        wnormconv_kernel<<<C_CLS / 4, 256, 0, stream>>>(w, wn);
        dim3 grid(NCHUNK, B_ROWS / BM);
        gemm_bf16_kernel<<<grid, 256, 0, stream>>>(xnb, wn, tgt, partials, tlogit);
        row_lse_kernel<<<B_ROWS, 256, 0, stream>>>(partials, tlogit, rowloss);
        final_mean_kernel<<<1, 256, 0, stream>>>(rowloss, out);
    } else {
        size_t off = 0;
        unsigned short* xnb = (unsigned short*)(ws + off); off += sz_xnb;
        off = (off + 255) & ~(size_t)255;
        float* rnorm = (float*)(ws + off); off += (size_t)C_CLS * 4;
        off = (off + 255) & ~(size_t)255;
        float2* partials = (float2*)(ws + off); off += sz_par;
        off = (off + 255) & ~(size_t)255;
        float* tlogit = (float*)(ws + off); off += 4096;
        float* rowloss = (float*)(ws + off); off += 4096;

        xnorm_kernel<<<B_ROWS, 256, 0, stream>>>(x, xnb);
        wnorm_kernel<<<C_CLS / 4, 256, 0, stream>>>(w, rnorm);
        dim3 grid(NCHUNK, B_ROWS / BM);
        gemm_fused_kernel<<<grid, 256, 0, stream>>>(xnb, w, rnorm, tgt, partials, tlogit);
        row_lse_kernel<<<B_ROWS, 256, 0, stream>>>(partials, tlogit, rowloss);
        final_mean_kernel<<<1, 256, 0, stream>>>(rowloss, out);
    }
}

// Round 3
// 125.678 us; speedup vs baseline: 2.0549x; 1.5937x over previous
//
#include <hip/hip_runtime.h>
#include <hip/hip_bf16.h>
#include <math.h>

// ---- problem constants ----
#define B_ROWS 512
#define D_K    512
#define C_CLS  100000
#define C_PAD  100032                   // padded to 64-chunk boundary (pad rows zeroed)

#define S_SCALE 64.0f
#define COS_M 0.8775825618903728f
#define SIN_M 0.479425538604203f
#define TH_C  (-0.8775825618903728f)    // cos(pi - m)
#define MM_C  0.2397127693021015f       // sin(pi - m) * m

#define LOG2E_S 92.33248261689366f      // 64 * log2(e)
#define M0      92.4f                   // fixed softmax max bound: |cos|<=1 -> |L|<=92.33
#define LN2F    0.6931471805599453f

// ---- GEMM tile config ----
#define BM 128
#define BN 64
#define NCHUNK (C_PAD / BN)             // 1563
#define CPS 13                          // chunks per strip
#define NSTRIP ((NCHUNK + CPS - 1) / CPS) // 121

typedef __attribute__((ext_vector_type(8))) short short8;
typedef __attribute__((ext_vector_type(4))) float f32x4;

__device__ inline unsigned short f2bf(float f) {
    unsigned int u = __float_as_uint(f);
    u += 0x7fffu + ((u >> 16) & 1u);
    return (unsigned short)(u >> 16);
}
__device__ inline float bf2f(unsigned short h) {
    return __uint_as_float(((unsigned int)h) << 16);
}
__device__ inline float fexp2(float x) {
#if __has_builtin(__builtin_amdgcn_exp2f)
    return __builtin_amdgcn_exp2f(x);
#else
    return exp2f(x);
#endif
}
__device__ inline void gload16(const void* g, void* lds) {
    __builtin_amdgcn_global_load_lds(
        (const __attribute__((address_space(1))) unsigned int*)g,
        (__attribute__((address_space(3))) unsigned int*)lds, 16, 0, 0);
}

#define VMCNT0() asm volatile("s_waitcnt vmcnt(0)" ::: "memory")
#define VMCNT2() asm volatile("s_waitcnt vmcnt(2)" ::: "memory")
#define VMCNT4() asm volatile("s_waitcnt vmcnt(4)" ::: "memory")
#define RAWBAR() __builtin_amdgcn_s_barrier()

// ---------------- kernel 0a: normalize x rows -> bf16 ----------------
__global__ __launch_bounds__(256) void xnorm_kernel(const float* __restrict__ x,
                                                    unsigned short* __restrict__ xnb) {
    const int row = blockIdx.x;
    const int t = threadIdx.x;
    float a = x[row * D_K + t];
    float b = x[row * D_K + t + 256];
    float s = a * a + b * b;
    s += __shfl_xor(s, 1);  s += __shfl_xor(s, 2);  s += __shfl_xor(s, 4);
    s += __shfl_xor(s, 8);  s += __shfl_xor(s, 16); s += __shfl_xor(s, 32);
    __shared__ float sS[4];
    __shared__ float rn_sh;
    if ((t & 63) == 0) sS[t >> 6] = s;
    __syncthreads();
    if (t == 0) rn_sh = 1.0f / sqrtf(sS[0] + sS[1] + sS[2] + sS[3]);
    __syncthreads();
    const float rn = rn_sh;
    xnb[row * D_K + t]       = f2bf(a * rn);
    xnb[row * D_K + t + 256] = f2bf(b * rn);
}

// ---------------- kernel 0b: normalize W rows -> bf16 (zero pad rows) ----------------
__global__ __launch_bounds__(256) void wnormconv_kernel(const float* __restrict__ w,
                                                        unsigned short* __restrict__ wn) {
    const int wid = threadIdx.x >> 6;
    const int lane = threadIdx.x & 63;
    const int c = blockIdx.x * 4 + wid;
    if (c >= C_CLS) {
        short8 z = {0,0,0,0,0,0,0,0};
        if (c < C_PAD) *(short8*)&wn[(size_t)c * D_K + lane * 8] = z;
        return;
    }
    const float* row = w + (size_t)c * D_K;
    float4 v1 = *(const float4*)&row[lane * 8];
    float4 v2 = *(const float4*)&row[lane * 8 + 4];
    float s = v1.x * v1.x + v1.y * v1.y + v1.z * v1.z + v1.w * v1.w
            + v2.x * v2.x + v2.y * v2.y + v2.z * v2.z + v2.w * v2.w;
    s += __shfl_xor(s, 1);  s += __shfl_xor(s, 2);  s += __shfl_xor(s, 4);
    s += __shfl_xor(s, 8);  s += __shfl_xor(s, 16); s += __shfl_xor(s, 32);
    const float rn = 1.0f / sqrtf(s);
    short8 h;
    h[0] = (short)f2bf(v1.x * rn);
    h[1] = (short)f2bf(v1.y * rn);
    h[2] = (short)f2bf(v1.z * rn);
    h[3] = (short)f2bf(v1.w * rn);
    h[4] = (short)f2bf(v2.x * rn);
    h[5] = (short)f2bf(v2.y * rn);
    h[6] = (short)f2bf(v2.z * rn);
    h[7] = (short)f2bf(v2.w * rn);
    *(short8*)&wn[(size_t)c * D_K + lane * 8] = h;
}

// ---------------- kernel 1: strip-persistent GEMM + fixed-M0 sumexp ----------------
// Block: 4 waves, BM=128 rows (A fully in registers), strip of CPS 64-class chunks.
// LDS: 4 x 8KB B buffers, depth-3 prefetch, counted vmcnt + raw s_barrier.
// Output: partials[strip][row] = sum over strip classes of 2^(S*log2e*cos - M0).
__global__ __launch_bounds__(256, 2) void gemm_strip_kernel(
        const unsigned short* __restrict__ xnb,   // [512][512] bf16 normalized
        const unsigned short* __restrict__ wn,    // [C_PAD][512] bf16 normalized (pad=0)
        float* __restrict__ partials) {           // [NSTRIP][512]
    const int t    = threadIdx.x;
    const int lane = t & 63;
    const int wid  = t >> 6;
    const int strip = blockIdx.x;
    const int R0    = blockIdx.y * BM;
    const int cbase = strip * (CPS * BN);
    const int rem   = NCHUNK - strip * CPS;
    const int nch   = rem < CPS ? rem : CPS;

    __shared__ char smem[4 * 8192];

    const int l8    = lane >> 3;
    const int cbs   = ((lane & 7) ^ l8) << 4;      // pre-swizzled global source byte-col
    const int cl    = lane & 15;
    const int khalf = (lane >> 4) << 4;
    const int xorv  = (lane & 7) << 4;

    const char* gA = (const char*)xnb;
    const char* gB = (const char*)wn;

    // ---- prologue: A[128][512] -> registers via LDS bounce (8 k-slices) ----
    short8 afr[2][16];
#pragma unroll
    for (int ks = 0; ks < 8; ++ks) {
#pragma unroll
        for (int i = 0; i < 4; ++i) {
            const int row = i * 32 + wid * 8 + l8;
            gload16(gA + (size_t)(R0 + row) * 1024 + ks * 128 + cbs,
                    smem + (i * 4 + wid) * 1024);
        }
        VMCNT0();
        __syncthreads();
#pragma unroll
        for (int m = 0; m < 2; ++m)
#pragma unroll
            for (int kk = 0; kk < 2; ++kk) {
                const int r = wid * 32 + m * 16 + cl;
                afr[m][ks * 2 + kk] =
                    *(const short8*)(smem + r * 128 + ((kk * 64 + khalf) ^ xorv));
            }
        __syncthreads();
    }

#define STAGE_B(ci, ks, bi)                                                        \
    {                                                                              \
        _Pragma("unroll")                                                          \
        for (int j = 0; j < 2; ++j) {                                              \
            const int crow = cbase + (ci) * 64 + j * 32 + wid * 8 + l8;            \
            gload16(gB + (size_t)crow * 1024 + (ks) * 128 + cbs,                   \
                    smem + (bi) * 8192 + (j * 4 + wid) * 1024);                    \
        }                                                                          \
    }

    // prologue stages for steps 0,1,2 (chunk 0, slices 0..2)
    STAGE_B(0, 0, 0);
    STAGE_B(0, 1, 1);
    STAGE_B(0, 2, 2);

    float sums[8] = {0.f, 0.f, 0.f, 0.f, 0.f, 0.f, 0.f, 0.f};

    for (int i = 0; i < nch; ++i) {
        f32x4 acc[2][4];
#pragma unroll
        for (int m = 0; m < 2; ++m)
#pragma unroll
            for (int n = 0; n < 4; ++n) acc[m][n] = (f32x4){0.f, 0.f, 0.f, 0.f};

#pragma unroll
        for (int k0 = 0; k0 < 8; ++k0) {
            // wait for stage(s) (s = i*8+k0); tail of last chunk drains deeper
            if (k0 == 6) {
                if (i == nch - 1) { VMCNT2(); } else { VMCNT4(); }
            } else if (k0 == 7) {
                if (i == nch - 1) { VMCNT0(); } else { VMCNT4(); }
            } else {
                VMCNT4();
            }
            RAWBAR();
            // issue stage(s+3) -> buffer (k0+3)&3 (static)
            {
                const int ci3 = i + ((k0 + 3) >> 3);
                const int ks3 = (k0 + 3) & 7;
                if (ci3 < nch) STAGE_B(ci3, ks3, (k0 + 3) & 3);
            }
            // compute from buffer k0&3
            const char* sB = smem + (k0 & 3) * 8192;
#pragma unroll
            for (int kk = 0; kk < 2; ++kk) {
                const int coff = (kk * 64 + khalf) ^ xorv;
                short8 bfr[4];
#pragma unroll
                for (int n = 0; n < 4; ++n)
                    bfr[n] = *(const short8*)(sB + (n * 16 + cl) * 128 + coff);
#pragma unroll
                for (int m = 0; m < 2; ++m)
#pragma unroll
                    for (int n = 0; n < 4; ++n)
                        acc[m][n] = __builtin_amdgcn_mfma_f32_16x16x32_bf16(
                            afr[m][k0 * 2 + kk], bfr[n], acc[m][n], 0, 0, 0);
            }
            if (k0 == 7) {
                // fixed-M0 online accumulation: sum += 2^(S*log2e*cos - M0)
#pragma unroll
                for (int m = 0; m < 2; ++m)
#pragma unroll
                    for (int j = 0; j < 4; ++j) {
#pragma unroll
                        for (int n = 0; n < 4; ++n)
                            sums[m * 4 + j] +=
                                fexp2(fmaf(acc[m][n][j], LOG2E_S, -M0));
                    }
            }
        }
    }

    // ---- strip epilogue: reduce each tracked row across its 16 col-lanes ----
#pragma unroll
    for (int m = 0; m < 2; ++m)
#pragma unroll
        for (int j = 0; j < 4; ++j) {
            float v = sums[m * 4 + j];
            v += __shfl_xor(v, 1);
            v += __shfl_xor(v, 2);
            v += __shfl_xor(v, 4);
            v += __shfl_xor(v, 8);
            if ((lane & 15) == 0) {
                const int r = R0 + wid * 32 + m * 16 + (lane >> 4) * 4 + j;
                partials[strip * B_ROWS + r] = v;
            }
        }
#undef STAGE_B
}

// ---------------- kernel 2: target-class dot (bf16 inputs, fp32 accum) ----------------
__global__ __launch_bounds__(256) void tdot_kernel(const unsigned short* __restrict__ xnb,
                                                   const unsigned short* __restrict__ wn,
                                                   const int* __restrict__ tgt,
                                                   float* __restrict__ tdot) {
    const int wid = threadIdx.x >> 6;
    const int lane = threadIdx.x & 63;
    const int b = blockIdx.x * 4 + wid;
    const int tg = tgt[b];
    short8 xa = *(const short8*)&xnb[(size_t)b * D_K + lane * 8];
    short8 wa = *(const short8*)&wn[(size_t)tg * D_K + lane * 8];
    float s = 0.f;
#pragma unroll
    for (int e = 0; e < 8; ++e)
        s += bf2f((unsigned short)xa[e]) * bf2f((unsigned short)wa[e]);
    s += __shfl_xor(s, 1);  s += __shfl_xor(s, 2);  s += __shfl_xor(s, 4);
    s += __shfl_xor(s, 8);  s += __shfl_xor(s, 16); s += __shfl_xor(s, 32);
    if (lane == 0) tdot[b] = s;
}

// ---------------- kernel 3: per-row loss (margin fixup) + mean ----------------
__global__ __launch_bounds__(512) void final_kernel(const float* __restrict__ partials,
                                                    const float* __restrict__ tdot,
                                                    float* __restrict__ out) {
    const int b = threadIdx.x;   // 512 threads = 8 waves
    float s2 = 0.f;
    for (int s = 0; s < NSTRIP; ++s) s2 += partials[s * B_ROWS + b];
    const float cst = tdot[b];
    float c2 = 1.0f - cst * cst;
    c2 = fminf(fmaxf(c2, 0.0f), 1.0f);
    const float sine = sqrtf(c2);
    float phi = cst * COS_M - sine * SIN_M;
    phi = (cst > TH_C) ? phi : (cst - MM_C);
    const float Lt = cst * LOG2E_S;
    const float Lp = phi * LOG2E_S;
    // swap plain-target term for margin term in the denominator
    s2 = s2 - fexp2(Lt - M0) + fexp2(Lp - M0);
    float loss = LN2F * (M0 + log2f(s2) - Lp);
    // mean over 512 rows
    loss += __shfl_xor(loss, 1);  loss += __shfl_xor(loss, 2);
    loss += __shfl_xor(loss, 4);  loss += __shfl_xor(loss, 8);
    loss += __shfl_xor(loss, 16); loss += __shfl_xor(loss, 32);
    __shared__ float sW[8];
    if ((b & 63) == 0) sW[b >> 6] = loss;
    __syncthreads();
    if (b == 0) {
        float tot = 0.f;
#pragma unroll
        for (int w = 0; w < 8; ++w) tot += sW[w];
        out[0] = tot * (1.0f / (float)B_ROWS);
    }
}

extern "C" void kernel_launch(void* const* d_in, const int* in_sizes, int n_in,
                              void* d_out, int out_size, void* d_ws, size_t ws_size,
                              hipStream_t stream) {
    const float* x = (const float*)d_in[0];
    const float* w = (const float*)d_in[1];
    const int* tgt = (const int*)d_in[2];
    float* out = (float*)d_out;

    char* ws = (char*)d_ws;
    size_t off = 0;
    unsigned short* xnb = (unsigned short*)(ws + off);
    off += (size_t)B_ROWS * D_K * 2;                       // 512 KB
    off = (off + 255) & ~(size_t)255;
    unsigned short* wn = (unsigned short*)(ws + off);
    off += (size_t)C_PAD * D_K * 2;                        // 102.4 MB
    off = (off + 255) & ~(size_t)255;
    float* partials = (float*)(ws + off);
    off += (size_t)NSTRIP * B_ROWS * 4;                    // 248 KB
    off = (off + 255) & ~(size_t)255;
    float* tdot = (float*)(ws + off);
    off += B_ROWS * 4;

    xnorm_kernel<<<B_ROWS, 256, 0, stream>>>(x, xnb);
    wnormconv_kernel<<<C_PAD / 4, 256, 0, stream>>>(w, wn);
    dim3 grid(NSTRIP, B_ROWS / BM);
    gemm_strip_kernel<<<grid, 256, 0, stream>>>(xnb, wn, partials);
    tdot_kernel<<<B_ROWS / 4, 256, 0, stream>>>(xnb, wn, tgt, tdot);
    final_kernel<<<1, 512, 0, stream>>>(partials, tdot, out);
}